// Round 1
// baseline (30.322 us; speedup 1.0000x reference)
//
#include <hip/hip_runtime.h>
#include <hip/hip_bf16.h>

// Problem constants (from setup_inputs): B=8, C=3, H=512, W=512, K=17.
// Output = per-pixel max over 16 segments of clip(lw+0.5 - dist(pixel,seg), 0, 1),
// broadcast to 3 channels. images' values are unused.

constexpr int BB   = 8;
constexpr int CC   = 3;
constexpr int HH   = 512;
constexpr int WW   = 512;
constexpr int KPTS = 17;
constexpr int NSEG = KPTS - 1;   // 16

__global__ __launch_bounds__(256)
void stroke_kernel(const float* __restrict__ traj,   // [B,K,4] (t,x,y,z)
                   const int*   __restrict__ lw_p,   // scalar line_width
                   float*       __restrict__ out)    // [B,C,H,W]
{
    __shared__ float sx0[NSEG], sy0[NSEG], sdx[NSEG], sdy[NSEG], srd[NSEG];

    // 256 blocks per batch item; each block covers 2 rows (2*512 px = 256 thr * 4 px).
    const int b  = blockIdx.x >> 8;          // / 256
    const int rb = (blockIdx.x & 255) << 1;  // base row of this block's 2-row strip

    const int tid = threadIdx.x;
    if (tid < NSEG) {
        const float* tb = traj + (size_t)b * KPTS * 4;
        float x0 = tb[tid * 4 + 1];
        float y0 = tb[tid * 4 + 2];
        float x1 = tb[tid * 4 + 5];
        float y1 = tb[tid * 4 + 6];
        float dx = x1 - x0, dy = y1 - y0;
        sx0[tid] = x0; sy0[tid] = y0;
        sdx[tid] = dx; sdy[tid] = dy;
        srd[tid] = 1.0f / (dx * dx + dy * dy + 1e-8f);
    }
    __syncthreads();

    const float lw = (float)(*lw_p) + 0.5f;

    const int row = rb + (tid >> 7);         // which of the 2 rows
    const int w0  = (tid & 127) << 2;        // 4 consecutive pixels
    const float fy = (float)row;

    float acc0 = 0.0f, acc1 = 0.0f, acc2 = 0.0f, acc3 = 0.0f;

    for (int s = 0; s < NSEG; ++s) {
        const float x0 = sx0[s], y0 = sy0[s];
        const float dx = sdx[s], dy = sdy[s], rd = srd[s];
        const float wy   = fy - y0;
        const float wydy = wy * dy;

        #pragma unroll
        for (int j = 0; j < 4; ++j) {
            float wx  = (float)(w0 + j) - x0;
            float t   = (wx * dx + wydy) * rd;
            t = fminf(fmaxf(t, 0.0f), 1.0f);
            float ddx = wx - t * dx;
            float ddy = wy - t * dy;
            float dist = sqrtf(ddx * ddx + ddy * ddy + 1e-12f);
            float cov  = fminf(fmaxf(lw - dist, 0.0f), 1.0f);
            if (j == 0) acc0 = fmaxf(acc0, cov);
            if (j == 1) acc1 = fmaxf(acc1, cov);
            if (j == 2) acc2 = fmaxf(acc2, cov);
            if (j == 3) acc3 = fmaxf(acc3, cov);
        }
    }

    const float4 v = make_float4(acc0, acc1, acc2, acc3);
    const size_t plane = (size_t)HH * WW;
    float* p = out + (size_t)b * CC * plane + (size_t)row * WW + w0;
    *reinterpret_cast<float4*>(p)             = v;
    *reinterpret_cast<float4*>(p + plane)     = v;
    *reinterpret_cast<float4*>(p + 2 * plane) = v;
}

extern "C" void kernel_launch(void* const* d_in, const int* in_sizes, int n_in,
                              void* d_out, int out_size, void* d_ws, size_t ws_size,
                              hipStream_t stream) {
    const float* traj = (const float*)d_in[1];   // trajectories [8,17,4]
    const int*   lw   = (const int*)d_in[2];     // line_width scalar
    float*       out  = (float*)d_out;           // [8,3,512,512] fp32

    dim3 grid(BB * (HH / 2));   // 8 * 256 = 2048 blocks
    dim3 block(256);
    stroke_kernel<<<grid, block, 0, stream>>>(traj, lw, out);
}

// Round 2
// 16.650 us; speedup vs baseline: 1.8212x; 1.8212x over previous
//
#include <hip/hip_runtime.h>
#include <hip/hip_bf16.h>

// B=8, C=3, H=512, W=512, K=17. Output = per-pixel max over 16 segments of
// clip(lw+0.5 - dist(pixel,seg), 0, 1), broadcast to 3 channels.
// images' values are unused.

constexpr int BB   = 8;
constexpr int CC   = 3;
constexpr int HH   = 512;
constexpr int WW   = 512;
constexpr int KPTS = 17;
constexpr int NSEG = KPTS - 1;   // 16

__global__ __launch_bounds__(256)
void stroke_kernel(const float* __restrict__ traj,   // [B,K,4] (t,x,y,z)
                   const int*   __restrict__ lw_p,   // scalar line_width
                   float*       __restrict__ out)    // [B,C,H,W]
{
    // 256 blocks per batch item; each block covers 2 rows (2*512 px = 256 thr * 4 px).
    const int b   = blockIdx.x >> 8;
    const int rb  = (blockIdx.x & 255) << 1;
    const int tid = threadIdx.x;

    const float lw = (float)(*lw_p) + 0.5f;   // uniform

    // Uniform knot loads (compiler -> s_load; no LDS, no __syncthreads).
    const float* tb = traj + b * (KPTS * 4);
    float px[KPTS], py[KPTS];
    #pragma unroll
    for (int k = 0; k < KPTS; ++k) {
        px[k] = tb[k * 4 + 1];
        py[k] = tb[k * 4 + 2];
    }

    const int row = rb + (tid >> 7);
    const int w0  = (tid & 127) << 2;
    const float fy  = (float)row;
    const float fx0 = (float)w0;
    const float fx3 = fx0 + 3.0f;

    float acc0 = 0.0f, acc1 = 0.0f, acc2 = 0.0f, acc3 = 0.0f;

    #pragma unroll
    for (int s = 0; s < NSEG; ++s) {
        const float x0 = px[s],     y0 = py[s];
        const float x1 = px[s + 1], y1 = py[s + 1];
        const float dx = x1 - x0,   dy = y1 - y0;
        const float xlo = fminf(x0, x1), xhi = fmaxf(x0, x1);
        const float ylo = fminf(y0, y1), yhi = fmaxf(y0, y1);

        // Distance from any of this thread's 4 pixels to the segment is at
        // least the axis gap to the segment bbox; if that already >= lw,
        // coverage is exactly 0 -> skip (wave-level execz when all lanes agree).
        const bool skip = (ylo - fy  >= lw) | (fy  - yhi >= lw) |
                          (xlo - fx3 >= lw) | (fx0 - xhi >= lw);
        if (!skip) {
            const float rd   = __builtin_amdgcn_rcpf(dx * dx + dy * dy + 1e-8f);
            const float wy   = fy - y0;
            const float wydy = wy * dy;
            #pragma unroll
            for (int j = 0; j < 4; ++j) {
                const float wx  = (fx0 + (float)j) - x0;
                float t = (wx * dx + wydy) * rd;
                t = fminf(fmaxf(t, 0.0f), 1.0f);
                const float ddx  = wx - t * dx;
                const float ddy  = wy - t * dy;
                const float d2   = ddx * ddx + (ddy * ddy + 1e-12f);
                const float dist = __builtin_amdgcn_sqrtf(d2);
                // lower clamp at 0 is implied by acc >= 0
                const float cov  = fminf(lw - dist, 1.0f);
                if (j == 0) acc0 = fmaxf(acc0, cov);
                if (j == 1) acc1 = fmaxf(acc1, cov);
                if (j == 2) acc2 = fmaxf(acc2, cov);
                if (j == 3) acc3 = fmaxf(acc3, cov);
            }
        }
    }

    const float4 v = make_float4(acc0, acc1, acc2, acc3);
    const size_t plane = (size_t)HH * WW;
    float* p = out + (size_t)b * CC * plane + (size_t)row * WW + w0;
    *reinterpret_cast<float4*>(p)             = v;
    *reinterpret_cast<float4*>(p + plane)     = v;
    *reinterpret_cast<float4*>(p + 2 * plane) = v;
}

extern "C" void kernel_launch(void* const* d_in, const int* in_sizes, int n_in,
                              void* d_out, int out_size, void* d_ws, size_t ws_size,
                              hipStream_t stream) {
    const float* traj = (const float*)d_in[1];   // trajectories [8,17,4]
    const int*   lw   = (const int*)d_in[2];     // line_width scalar
    float*       out  = (float*)d_out;           // [8,3,512,512] fp32

    dim3 grid(BB * (HH / 2));   // 2048 blocks
    dim3 block(256);
    stroke_kernel<<<grid, block, 0, stream>>>(traj, lw, out);
}